// Round 10
// baseline (155.706 us; speedup 1.0000x reference)
//
#include <hip/hip_runtime.h>
#include <math.h>

// ---------------------------------------------------------------------------
// N=4, T=2048, D_MODEL=512, NHEAD=8, HEAD_DIM=64, window -127..+128.
// Pipeline: cvt_all -> bf16 ; qkv = x@Wqkv^T + fused RoPE + q-scale (MFMA,
// LDS-staged BM=128 BN=64 BK=64, XOR-swizzled, global_load_lds) ; flash attn
// (MFMA, swapped-QK^T in-register softmax, NO K/V staging, barrier-free) ;
// out GEMM.
// R23: attn K/V LDS staging DROPPED (Common-mistake #7 / m169): K+V per
// (n,h) is 512KB (L2-resident); each 8KB tile is read by 5 blocks x 4 waves,
// rows are exactly cache-line-granular (128B @ 128B alignment), and a
// block's 4 waves share L1. kf/vf now load straight from global; staging,
// vmcnt drain, and BOTH barriers deleted (kernel is barrier-free; only LDS
// left is the wave-private Ps). MFMA inputs bitwise identical -> absmax must
// stay 0.0004882812. R20/R21/R22 lesson: any added attn structure regressed;
// this REMOVES structure.
// R19: Ps needs no barrier (wave-private, program-ordered DS) — kept.
// R17: swapped QK^T in-register softmax (kept). R18 lesson: counted-vmcnt
// 2-phase GEMM regressed; GEMM schedule frozen at BN=64/BK=64/(256,5).
// R15/R20 lessons: 256-thr/5-blocks-CU occupancy is the sticky optimum.
// R14: V pre-transposed to vT[n][h][d][t] by the QKV GEMM (kept).
// ---------------------------------------------------------------------------

typedef __attribute__((ext_vector_type(8))) __bf16 bf16x8;
typedef __attribute__((ext_vector_type(4))) float f32x4;

__device__ __forceinline__ unsigned short f2bf(float f) {
    unsigned int u = __float_as_uint(f);
    u += 0x7fffu + ((u >> 16) & 1u);
    return (unsigned short)(u >> 16);
}
__device__ __forceinline__ unsigned int packbf2(float a, float b) {
    unsigned int ua = __float_as_uint(a); ua += 0x7fffu + ((ua >> 16) & 1u);
    unsigned int ub = __float_as_uint(b); ub += 0x7fffu + ((ub >> 16) & 1u);
    return (ua >> 16) | (ub & 0xffff0000u);
}
__device__ __forceinline__ bf16x8 as_bf16x8(uint4 u) {
    union { uint4 u4; bf16x8 v; } c; c.u4 = u; return c.v;
}
__device__ __forceinline__ bf16x8 ld_frag(const unsigned short* p) {
    return as_bf16x8(*(const uint4*)p);
}

__device__ __forceinline__ void async16(void* lds, const void* g) {
    __builtin_amdgcn_global_load_lds(
        (const __attribute__((address_space(1))) void*)g,
        (__attribute__((address_space(3))) void*)lds,
        16, 0, 0);
}

// One kernel converts all three fp32 inputs to bf16 (4 elems/thread).
__global__ __launch_bounds__(256) void cvt_all(
    const float* __restrict__ x, const float* __restrict__ w1,
    const float* __restrict__ w2,
    unsigned short* __restrict__ xb, unsigned short* __restrict__ w1b,
    unsigned short* __restrict__ w2b)
{
    const int n_x  = 8192 * 512 / 4;
    const int n_w1 = 1536 * 512 / 4;
    const int n_w2 = 512 * 512 / 4;
    int i = blockIdx.x * 256 + threadIdx.x;
    const float* in; unsigned short* out; int j;
    if (i < n_x)                    { in = x;  out = xb;  j = i; }
    else if (i < n_x + n_w1)        { in = w1; out = w1b; j = i - n_x; }
    else if (i < n_x + n_w1 + n_w2) { in = w2; out = w2b; j = i - n_x - n_w1; }
    else return;
    float4 v = *(const float4*)(in + 4 * (size_t)j);
    uint2 o;
    o.x = packbf2(v.x, v.y);
    o.y = packbf2(v.z, v.w);
    *(uint2*)(out + 4 * (size_t)j) = o;
}

// C[M,O] = A[M,K](bf16) * B[O,K](bf16)^T (+bias). Output fp32 or bf16.
// BM=128, BN=64, BK=64. Block=256 (4 waves); wave w computes rows
// [w*32,+32) x all 64 cols (mt=2, nt=4; acc 32 AGPR).
// __launch_bounds__(256,5): target 5 blocks/CU (~102-reg cap) so barrier
// drains overlap across resident blocks. (R15/R18 lessons: occupancy beats
// density AND beats counted-vmcnt pipelining at K=512 — schedule frozen.)
// Grid: blockIdx.x = ROW block (fastest; R11 showed col-fastest regresses).
// LDS XOR-swizzled k-offset: staging dests stay chunk-contiguous
// (global_load_lds constraint), frag reads conflict-free.
// do_rope: qkv layout (O=1536); RoPE cols<1024 (partner col^32 == acc nt^2,
// same thread), fold 1/8 into q cols<512. V cols (>=1024) are written
// transposed to vT[n][h][dim][t] as packed 8B stores (attn consumes V^T).
__global__ __launch_bounds__(256, 5) void gemm_bt_mfma(
    const unsigned short* __restrict__ A, const unsigned short* __restrict__ B,
    const float* __restrict__ bias, void* __restrict__ Cout,
    int M, int O, int K, int write_bf16, int do_rope,
    unsigned short* __restrict__ vT)
{
    __shared__ __align__(16) unsigned short As[128 * 64];   // 16 KB
    __shared__ __align__(16) unsigned short Bs[64 * 64];    // 8 KB

    const int tid  = threadIdx.x;
    const int wave = tid >> 6;
    const int lane = tid & 63;
    const int l15  = lane & 15;
    const int lg   = lane >> 4;
    const int row0 = blockIdx.x * 128;
    const int col0 = blockIdx.y * 64;
    const int wr   = wave * 32;

    f32x4 acc[2][4] = {};

    const int srow = tid >> 3;
    const int skg  = ((tid & 7) * 8) ^ ((srow & 7) * 8);
    const int fx   = (l15 & 7) * 8;

    for (int k0 = 0; k0 < K; k0 += 64) {
        #pragma unroll
        for (int s = 0; s < 4; ++s)
            async16(&As[(size_t)(s * 256 + tid) * 8],
                    A + (size_t)(row0 + s * 32 + srow) * K + k0 + skg);
        #pragma unroll
        for (int s = 0; s < 2; ++s)
            async16(&Bs[(size_t)(s * 256 + tid) * 8],
                    B + (size_t)(col0 + s * 32 + srow) * K + k0 + skg);
        __syncthreads();

        #pragma unroll
        for (int kstep = 0; kstep < 2; ++kstep) {
            const int kq = (kstep * 32 + lg * 8) ^ fx;
            bf16x8 af[2], bfr[4];
            #pragma unroll
            for (int mt = 0; mt < 2; ++mt)
                af[mt] = ld_frag(&As[(wr + mt * 16 + l15) * 64 + kq]);
            #pragma unroll
            for (int nt = 0; nt < 4; ++nt)
                bfr[nt] = ld_frag(&Bs[(nt * 16 + l15) * 64 + kq]);
            #pragma unroll
            for (int mt = 0; mt < 2; ++mt)
                #pragma unroll
                for (int nt = 0; nt < 4; ++nt)
                    acc[mt][nt] = __builtin_amdgcn_mfma_f32_16x16x32_bf16(
                        af[mt], bfr[nt], acc[mt][nt], 0, 0, 0);
        }
        __syncthreads();
    }

    const int qrow = lg * 4;

    // Fused RoPE: col = col0 + nt*16 + l15, col0 mult of 64 -> d = nt*16+l15.
    // i = d&31 -> (nt&1)*16+l15 ; partner d^32 = acc nt^2 (same thread).
    if (do_rope && col0 < 1024) {
        const float cfreq = 0.28782313662425574f;   // ln(10000)/32
        const float invf0 = __expf(-(float)l15 * cfreq);
        const float invf1 = __expf(-(float)(16 + l15) * cfreq);
        #pragma unroll
        for (int mt = 0; mt < 2; ++mt) {
            #pragma unroll
            for (int r = 0; r < 4; ++r) {
                const int t = (row0 + wr + mt * 16 + qrow + r) & 2047;
                #pragma unroll
                for (int p = 0; p < 2; ++p) {
                    float ang = (float)t * (p ? invf1 : invf0);
                    float s, c;
                    __sincosf(ang, &s, &c);
                    float a = acc[mt][p][r];       // d = p*16+l15 (< 32)
                    float b = acc[mt][p + 2][r];   // d = 32 + p*16+l15
                    acc[mt][p][r]     = a * c - b * s;
                    acc[mt][p + 2][r] = b * c + a * s;
                }
            }
        }
        if (col0 < 512) {   // q: fold softmax scale 1/sqrt(64)
            #pragma unroll
            for (int mt = 0; mt < 2; ++mt)
                #pragma unroll
                for (int nt = 0; nt < 4; ++nt)
                    #pragma unroll
                    for (int r = 0; r < 4; ++r)
                        acc[mt][nt][r] *= 0.125f;
        }
    }

    if (do_rope && col0 >= 1024) {
        // V columns: write transposed into vT[n][h][dim][t] (bf16).
        // Rows rowb..rowb+3 are consecutive t within one n -> one 8B store.
        #pragma unroll
        for (int nt = 0; nt < 4; ++nt) {
            const int local = col0 - 1024 + nt * 16 + l15;
            const int hh = local >> 6;
            const int dd = local & 63;
            #pragma unroll
            for (int mt = 0; mt < 2; ++mt) {
                const int rowb = row0 + wr + mt * 16 + qrow;
                const int nn = rowb >> 11;
                const int tt = rowb & 2047;
                uint2 o;
                o.x = packbf2(acc[mt][nt][0], acc[mt][nt][1]);
                o.y = packbf2(acc[mt][nt][2], acc[mt][nt][3]);
                *(uint2*)(vT + ((size_t)(nn * 8 + hh) * 64 + dd) * 2048 + tt) = o;
            }
        }
        return;
    }

    #pragma unroll
    for (int nt = 0; nt < 4; ++nt) {
        const int col = col0 + nt * 16 + l15;
        const float bv = bias ? bias[col] : 0.f;
        #pragma unroll
        for (int mt = 0; mt < 2; ++mt) {
            const int rowb = row0 + wr + mt * 16 + qrow;
            if (write_bf16) {
                unsigned short* C = (unsigned short*)Cout;
                #pragma unroll
                for (int r = 0; r < 4; ++r)
                    C[(size_t)(rowb + r) * O + col] = f2bf(acc[mt][nt][r] + bv);
            } else {
                float* C = (float*)Cout;
                #pragma unroll
                for (int r = 0; r < 4; ++r)
                    C[(size_t)(rowb + r) * O + col] = acc[mt][nt][r] + bv;
            }
        }
    }
}

// Flash attention with MFMA. Block=256 (4 waves) handles (qt, h, n).
// R23: NO K/V LDS staging — kf/vf load straight from global (K rows'
// 128B segments are cache-line aligned; vT rows dense; a block's 4 waves
// share L1, tiles are L2-resident). Kernel is BARRIER-FREE; only LDS is the
// wave-private Ps. MFMA inputs bitwise identical to the staged versions.
// R17: swapped QK^T — acc_s = mfma(kf, qfrag) computes S^T: row=key
// (nt*16+lg*4+r), col=query (l15). Thread owns ONE query, 16 scores in regs;
// softmax = in-reg max/sum + 2 shfl_xor; P written as 4x packed ds_write_b64
// into Ps[q][k]; alpha and 1/l redistributed to PV layout (query=lg*4+r)
// via 4 shfl. Fully-masked-tile semantics preserved (m stays -1e30; first
// valid tile's alpha=0 wipes garbage). q pre-scaled by 1/8 in the QKV GEMM.
__global__ __launch_bounds__(256) void attn_mfma_kernel(
    const unsigned short* __restrict__ qkv,
    const unsigned short* __restrict__ vT,
    unsigned short* __restrict__ attnout)
{
    __shared__ __align__(16) unsigned short Ps[4][16 * 72];   // per-wave P[q][k]

    const int qt = blockIdx.x;
    const int h  = blockIdx.y;
    const int n  = blockIdx.z;
    const int t0 = qt * 64;
    const int tid  = threadIdx.x;
    const int wave = tid >> 6;
    const int lane = tid & 63;
    const int l15  = lane & 15;
    const int lg   = lane >> 4;
    const int qrow = lg * 4;

    const size_t base = (size_t)n * 2048 * 1536 + (size_t)h * 64;
    const unsigned short* kall = qkv + base + 512;
    const unsigned short* vTh  = vT + (size_t)(n * 8 + h) * 64 * 2048;

    bf16x8 qfrag[2];
    {
        const unsigned short* qp = qkv + base + (size_t)(t0 + wave * 16 + l15) * 1536;
        qfrag[0] = ld_frag(qp + lg * 8);
        qfrag[1] = ld_frag(qp + 32 + lg * 8);
    }

    const int qq = wave * 16 + l15;       // this thread's query (within 64-tile)
    float m_v = -1e30f, l_v = 0.f;
    f32x4 acc_o[4] = {};

    for (int dt = -2; dt <= 2; ++dt) {
        const int kt = qt + dt;
        if (kt < 0 || kt > 31) continue;
        const int s0 = kt * 64;

        // ---- S^T = K Q^T, kf direct from global (skip dead edge subtiles) --
        f32x4 acc_s[4] = {};
        #pragma unroll
        for (int kstep = 0; kstep < 2; ++kstep) {
            #pragma unroll
            for (int nt = 0; nt < 4; ++nt) {
                if ((dt == -2 && nt < wave) || (dt == 2 && nt > wave)) continue;
                bf16x8 kf = ld_frag(kall +
                                    (size_t)(s0 + nt * 16 + l15) * 1536 +
                                    kstep * 32 + lg * 8);
                acc_s[nt] = __builtin_amdgcn_mfma_f32_16x16x32_bf16(
                    kf, qfrag[kstep], acc_s[nt], 0, 0, 0);
            }
        }

        // ---- per-thread softmax over 16 scores (one query = l15) ----
        float p[4][4];
        float tm = -1e30f;
        #pragma unroll
        for (int nt = 0; nt < 4; ++nt) {
            #pragma unroll
            for (int r = 0; r < 4; ++r) {
                const int diff = dt * 64 + nt * 16 + qrow + r - qq;
                const bool ok = (diff >= -127) && (diff <= 128);
                const float v = ok ? acc_s[nt][r] : -1e30f;   // scale folded in q
                p[nt][r] = v;
                tm = fmaxf(tm, v);
            }
        }
        tm = fmaxf(tm, __shfl_xor(tm, 16, 64));
        tm = fmaxf(tm, __shfl_xor(tm, 32, 64));
        const float m_new = fmaxf(m_v, tm);
        const float alpha = __expf(m_v - m_new);
        float psum = 0.f;
        #pragma unroll
        for (int nt = 0; nt < 4; ++nt) {
            #pragma unroll
            for (int r = 0; r < 4; ++r) {
                const float e = __expf(p[nt][r] - m_new);
                p[nt][r] = e;
                psum += e;
            }
        }
        psum += __shfl_xor(psum, 16, 64);
        psum += __shfl_xor(psum, 32, 64);
        l_v = l_v * alpha + psum;
        m_v = m_new;

        // rescale acc_o: alpha for query lg*4+r lives in lane (lane&48)|(qrow+r)
        #pragma unroll
        for (int r = 0; r < 4; ++r) {
            const float a_r = __shfl(alpha, (lane & 48) + qrow + r, 64);
            #pragma unroll
            for (int nt = 0; nt < 4; ++nt) acc_o[nt][r] *= a_r;
        }

        // P -> Ps[q][k]: k = nt*16 + qrow + {0..3} contiguous -> packed 8B.
        // Wave-private: no barrier before the pfrag read (same-wave DS order).
        #pragma unroll
        for (int nt = 0; nt < 4; ++nt) {
            uint2 o;
            o.x = packbf2(p[nt][0], p[nt][1]);
            o.y = packbf2(p[nt][2], p[nt][3]);
            *(uint2*)&Ps[wave][l15 * 72 + nt * 16 + qrow] = o;
        }

        bf16x8 pfrag[2];
        pfrag[0] = ld_frag(&Ps[wave][l15 * 72 + lg * 8]);
        pfrag[1] = ld_frag(&Ps[wave][l15 * 72 + 32 + lg * 8]);

        // ---- PV: vf direct from global vT (row=dim, dense cols) ----
        #pragma unroll
        for (int kstep = 0; kstep < 2; ++kstep) {
            #pragma unroll
            for (int nt = 0; nt < 4; ++nt) {
                bf16x8 vf = ld_frag(vTh + (size_t)(nt * 16 + l15) * 2048 +
                                    s0 + kstep * 32 + lg * 8);
                acc_o[nt] = __builtin_amdgcn_mfma_f32_16x16x32_bf16(
                    pfrag[kstep], vf, acc_o[nt], 0, 0, 0);
            }
        }
    }

    // 1/l for query lg*4+r lives in lane (lane&48)|(qrow+r)
    const float linv = 1.0f / l_v;
    float inv_l[4];
    #pragma unroll
    for (int r = 0; r < 4; ++r)
        inv_l[r] = __shfl(linv, (lane & 48) + qrow + r, 64);

    #pragma unroll
    for (int r = 0; r < 4; ++r) {
        const int tq = t0 + wave * 16 + qrow + r;
        unsigned short* op = attnout + (size_t)(n * 2048 + tq) * 512 + h * 64;
        #pragma unroll
        for (int nt = 0; nt < 4; ++nt)
            op[nt * 16 + l15] = f2bf(acc_o[nt][r] * inv_l[r]);
    }
}

extern "C" void kernel_launch(void* const* d_in, const int* in_sizes, int n_in,
                              void* d_out, int out_size, void* d_ws, size_t ws_size,
                              hipStream_t stream)
{
    (void)in_sizes; (void)n_in; (void)out_size; (void)ws_size;

    const float* x     = (const float*)d_in[0];
    const float* Wqkv  = (const float*)d_in[1];
    const float* out_w = (const float*)d_in[2];
    const float* out_b = (const float*)d_in[3];
    float* out = (float*)d_out;

    unsigned short* qkvb  = (unsigned short*)d_ws;          // 8192*1536 bf16
    unsigned short* attnb = qkvb + (size_t)8192 * 1536;     // 8192*512  bf16
    unsigned short* xb    = attnb + (size_t)8192 * 512;     // 8192*512  bf16
    unsigned short* wqkvb = xb + (size_t)8192 * 512;        // 1536*512  bf16
    unsigned short* outwb = wqkvb + (size_t)1536 * 512;     // 512*512   bf16
    unsigned short* vTb   = outwb + (size_t)512 * 512;      // 4*8*64*2048 bf16

    // 0) all fp32->bf16 conversions in one launch
    cvt_all<<<5120, 256, 0, stream>>>(x, Wqkv, out_w, xb, wqkvb, outwb);

    // 1) qkv = x @ Wqkv^T with fused RoPE + q-scale (bf16 out; V -> vT)
    gemm_bt_mfma<<<dim3(64, 24), 256, 0, stream>>>(xb, wqkvb, nullptr, qkvb,
                                                   8192, 1536, 512, 1, 1, vTb);
    // 2) flash attention -> attnb bf16 (barrier-free)
    attn_mfma_kernel<<<dim3(32, 8, 4), 256, 0, stream>>>(qkvb, vTb, attnb);
    // 3) out = attn @ out_w^T + out_b (fp32 out)
    gemm_bt_mfma<<<dim3(64, 8), 256, 0, stream>>>(attnb, outwb, out_b, out,
                                                  8192, 512, 512, 0, 0, nullptr);
}

// Round 11
// 127.816 us; speedup vs baseline: 1.2182x; 1.2182x over previous
//
#include <hip/hip_runtime.h>
#include <math.h>

// ---------------------------------------------------------------------------
// N=4, T=2048, D_MODEL=512, NHEAD=8, HEAD_DIM=64, window -127..+128.
// Pipeline: cvt_all -> bf16 ; qkv GEMM (MFMA, LDS-staged BM=128 BN=64 BK=64,
// XOR-swizzled, global_load_lds) + fused RoPE + q-scale, writing COMPACT
// per-head qb/kb and transposed vT ; flash attn (R19 structure, swapped-QK^T
// in-register softmax) ; out GEMM.
// R24: attn loop reverted to R19-exact (R23's direct-from-global operand
// loads were 16 cache lines/wave-instr on the MFMA dep chain: attn 25->53us,
// MfmaUtil 3.2% — LDS staging is load-bearing). ONE address-level change:
// GEMM1 writes q,k to COMPACT qb/kb[n*8+h][2048][64] (rows 128B dense, like
// vT) instead of strided qkvb; qkvb eliminated. Attn staging now reads 8KB
// contiguous per tile (2 lines/wave-instr vs 16) and Q loads are dense.
// Same store count in GEMM1 epilogue; attn loop byte-identical to R19 ->
// absmax must stay 0.0004882812.
// R19: Ps needs no barrier (wave-private, program-ordered DS) — kept.
// R17: swapped QK^T in-register softmax (kept). R18 lesson: counted-vmcnt
// 2-phase GEMM regressed; GEMM schedule frozen at BN=64/BK=64/(256,5).
// R15/R20 lessons: 256-thr/5-blocks-CU occupancy is the sticky optimum.
// R14: V pre-transposed to vT[n][h][d][t] by the QKV GEMM (kept).
// ---------------------------------------------------------------------------

typedef __attribute__((ext_vector_type(8))) __bf16 bf16x8;
typedef __attribute__((ext_vector_type(4))) float f32x4;

__device__ __forceinline__ unsigned short f2bf(float f) {
    unsigned int u = __float_as_uint(f);
    u += 0x7fffu + ((u >> 16) & 1u);
    return (unsigned short)(u >> 16);
}
__device__ __forceinline__ unsigned int packbf2(float a, float b) {
    unsigned int ua = __float_as_uint(a); ua += 0x7fffu + ((ua >> 16) & 1u);
    unsigned int ub = __float_as_uint(b); ub += 0x7fffu + ((ub >> 16) & 1u);
    return (ua >> 16) | (ub & 0xffff0000u);
}
__device__ __forceinline__ bf16x8 as_bf16x8(uint4 u) {
    union { uint4 u4; bf16x8 v; } c; c.u4 = u; return c.v;
}
__device__ __forceinline__ bf16x8 ld_frag(const unsigned short* p) {
    return as_bf16x8(*(const uint4*)p);
}

__device__ __forceinline__ void async16(void* lds, const void* g) {
    __builtin_amdgcn_global_load_lds(
        (const __attribute__((address_space(1))) void*)g,
        (__attribute__((address_space(3))) void*)lds,
        16, 0, 0);
}

// One kernel converts all three fp32 inputs to bf16 (4 elems/thread).
__global__ __launch_bounds__(256) void cvt_all(
    const float* __restrict__ x, const float* __restrict__ w1,
    const float* __restrict__ w2,
    unsigned short* __restrict__ xb, unsigned short* __restrict__ w1b,
    unsigned short* __restrict__ w2b)
{
    const int n_x  = 8192 * 512 / 4;
    const int n_w1 = 1536 * 512 / 4;
    const int n_w2 = 512 * 512 / 4;
    int i = blockIdx.x * 256 + threadIdx.x;
    const float* in; unsigned short* out; int j;
    if (i < n_x)                    { in = x;  out = xb;  j = i; }
    else if (i < n_x + n_w1)        { in = w1; out = w1b; j = i - n_x; }
    else if (i < n_x + n_w1 + n_w2) { in = w2; out = w2b; j = i - n_x - n_w1; }
    else return;
    float4 v = *(const float4*)(in + 4 * (size_t)j);
    uint2 o;
    o.x = packbf2(v.x, v.y);
    o.y = packbf2(v.z, v.w);
    *(uint2*)(out + 4 * (size_t)j) = o;
}

// C[M,O] = A[M,K](bf16) * B[O,K](bf16)^T (+bias). Output fp32 or bf16.
// BM=128, BN=64, BK=64. Block=256 (4 waves); wave w computes rows
// [w*32,+32) x all 64 cols (mt=2, nt=4; acc 32 AGPR).
// __launch_bounds__(256,5): target 5 blocks/CU (~102-reg cap) so barrier
// drains overlap across resident blocks. (R15/R18 lessons: occupancy beats
// density AND beats counted-vmcnt pipelining at K=512 — schedule frozen.)
// Grid: blockIdx.x = ROW block (fastest; R11 showed col-fastest regresses).
// LDS XOR-swizzled k-offset: staging dests stay chunk-contiguous
// (global_load_lds constraint), frag reads conflict-free.
// do_rope (qkv layout, O=1536): RoPE cols<1024 (partner col^32 == acc nt^2,
// same thread), fold 1/8 into q cols<512. Writes route to COMPACT buffers:
// cols<512 -> qb[n*8+h][t][64]; 512..1024 -> kb (same layout);
// >=1024 -> vT[n*8+h][dim][t] transposed (packed 8B stores).
__global__ __launch_bounds__(256, 5) void gemm_bt_mfma(
    const unsigned short* __restrict__ A, const unsigned short* __restrict__ B,
    const float* __restrict__ bias, void* __restrict__ Cout,
    int M, int O, int K, int write_bf16, int do_rope,
    unsigned short* __restrict__ vT,
    unsigned short* __restrict__ qbuf, unsigned short* __restrict__ kbuf)
{
    __shared__ __align__(16) unsigned short As[128 * 64];   // 16 KB
    __shared__ __align__(16) unsigned short Bs[64 * 64];    // 8 KB

    const int tid  = threadIdx.x;
    const int wave = tid >> 6;
    const int lane = tid & 63;
    const int l15  = lane & 15;
    const int lg   = lane >> 4;
    const int row0 = blockIdx.x * 128;
    const int col0 = blockIdx.y * 64;
    const int wr   = wave * 32;

    f32x4 acc[2][4] = {};

    const int srow = tid >> 3;
    const int skg  = ((tid & 7) * 8) ^ ((srow & 7) * 8);
    const int fx   = (l15 & 7) * 8;

    for (int k0 = 0; k0 < K; k0 += 64) {
        #pragma unroll
        for (int s = 0; s < 4; ++s)
            async16(&As[(size_t)(s * 256 + tid) * 8],
                    A + (size_t)(row0 + s * 32 + srow) * K + k0 + skg);
        #pragma unroll
        for (int s = 0; s < 2; ++s)
            async16(&Bs[(size_t)(s * 256 + tid) * 8],
                    B + (size_t)(col0 + s * 32 + srow) * K + k0 + skg);
        __syncthreads();

        #pragma unroll
        for (int kstep = 0; kstep < 2; ++kstep) {
            const int kq = (kstep * 32 + lg * 8) ^ fx;
            bf16x8 af[2], bfr[4];
            #pragma unroll
            for (int mt = 0; mt < 2; ++mt)
                af[mt] = ld_frag(&As[(wr + mt * 16 + l15) * 64 + kq]);
            #pragma unroll
            for (int nt = 0; nt < 4; ++nt)
                bfr[nt] = ld_frag(&Bs[(nt * 16 + l15) * 64 + kq]);
            #pragma unroll
            for (int mt = 0; mt < 2; ++mt)
                #pragma unroll
                for (int nt = 0; nt < 4; ++nt)
                    acc[mt][nt] = __builtin_amdgcn_mfma_f32_16x16x32_bf16(
                        af[mt], bfr[nt], acc[mt][nt], 0, 0, 0);
        }
        __syncthreads();
    }

    const int qrow = lg * 4;

    if (do_rope) {
        // Fused RoPE for q,k: col = col0 + nt*16 + l15 -> d = nt*16+l15;
        // partner d^32 = acc nt^2 (same thread).
        if (col0 < 1024) {
            const float cfreq = 0.28782313662425574f;   // ln(10000)/32
            const float invf0 = __expf(-(float)l15 * cfreq);
            const float invf1 = __expf(-(float)(16 + l15) * cfreq);
            #pragma unroll
            for (int mt = 0; mt < 2; ++mt) {
                #pragma unroll
                for (int r = 0; r < 4; ++r) {
                    const int t = (row0 + wr + mt * 16 + qrow + r) & 2047;
                    #pragma unroll
                    for (int p = 0; p < 2; ++p) {
                        float ang = (float)t * (p ? invf1 : invf0);
                        float s, c;
                        __sincosf(ang, &s, &c);
                        float a = acc[mt][p][r];       // d = p*16+l15 (< 32)
                        float b = acc[mt][p + 2][r];   // d = 32 + p*16+l15
                        acc[mt][p][r]     = a * c - b * s;
                        acc[mt][p + 2][r] = b * c + a * s;
                    }
                }
            }
            if (col0 < 512) {   // q: fold softmax scale 1/sqrt(64)
                #pragma unroll
                for (int mt = 0; mt < 2; ++mt)
                    #pragma unroll
                    for (int nt = 0; nt < 4; ++nt)
                        #pragma unroll
                        for (int r = 0; r < 4; ++r)
                            acc[mt][nt][r] *= 0.125f;
            }
            // write COMPACT qb/kb[nh][t][64]
            unsigned short* dst = (col0 < 512) ? qbuf : kbuf;
            const int cbase = (col0 < 512) ? col0 : col0 - 512;
            #pragma unroll
            for (int nt = 0; nt < 4; ++nt) {
                const int local = cbase + nt * 16 + l15;
                const int hh = local >> 6;
                const int dd = local & 63;
                #pragma unroll
                for (int mt = 0; mt < 2; ++mt) {
                    const int rowb = row0 + wr + mt * 16 + qrow;
                    const int nn = rowb >> 11;
                    const int tt = rowb & 2047;
                    unsigned short* p = dst +
                        ((size_t)(nn * 8 + hh) * 2048 + tt) * 64 + dd;
                    #pragma unroll
                    for (int r = 0; r < 4; ++r)
                        p[(size_t)r * 64] = f2bf(acc[mt][nt][r]);
                }
            }
        } else {
            // V columns: write transposed into vT[nh][dim][t] (bf16).
            #pragma unroll
            for (int nt = 0; nt < 4; ++nt) {
                const int local = col0 - 1024 + nt * 16 + l15;
                const int hh = local >> 6;
                const int dd = local & 63;
                #pragma unroll
                for (int mt = 0; mt < 2; ++mt) {
                    const int rowb = row0 + wr + mt * 16 + qrow;
                    const int nn = rowb >> 11;
                    const int tt = rowb & 2047;
                    uint2 o;
                    o.x = packbf2(acc[mt][nt][0], acc[mt][nt][1]);
                    o.y = packbf2(acc[mt][nt][2], acc[mt][nt][3]);
                    *(uint2*)(vT + ((size_t)(nn * 8 + hh) * 64 + dd) * 2048 + tt) = o;
                }
            }
        }
        return;
    }

    #pragma unroll
    for (int nt = 0; nt < 4; ++nt) {
        const int col = col0 + nt * 16 + l15;
        const float bv = bias ? bias[col] : 0.f;
        #pragma unroll
        for (int mt = 0; mt < 2; ++mt) {
            const int rowb = row0 + wr + mt * 16 + qrow;
            if (write_bf16) {
                unsigned short* C = (unsigned short*)Cout;
                #pragma unroll
                for (int r = 0; r < 4; ++r)
                    C[(size_t)(rowb + r) * O + col] = f2bf(acc[mt][nt][r] + bv);
            } else {
                float* C = (float*)Cout;
                #pragma unroll
                for (int r = 0; r < 4; ++r)
                    C[(size_t)(rowb + r) * O + col] = acc[mt][nt][r] + bv;
            }
        }
    }
}

// Flash attention with MFMA. Block=256 (4 waves) handles (qt, h, n).
// R19-exact loop; R24: Q/K read from COMPACT qb/kb[nh][t][64] (rows 128B
// dense) — staging reads 8KB contiguous per tile (fully coalesced), Q frag
// loads dense. V from vT as before. 2 barriers/tile.
// R17: swapped QK^T — acc_s = mfma(kf, qfrag) computes S^T: row=key
// (nt*16+lg*4+r), col=query (l15). Thread owns ONE query, 16 scores in regs;
// softmax = in-reg max/sum + 2 shfl_xor; P written as 4x packed ds_write_b64
// into Ps[q][k]; alpha and 1/l redistributed to PV layout (query=lg*4+r)
// via 4 shfl. Fully-masked-tile semantics preserved (m stays -1e30; first
// valid tile's alpha=0 wipes garbage). q pre-scaled by 1/8 in the QKV GEMM.
__global__ __launch_bounds__(256) void attn_mfma_kernel(
    const unsigned short* __restrict__ qb,
    const unsigned short* __restrict__ kb,
    const unsigned short* __restrict__ vT,
    unsigned short* __restrict__ attnout)
{
    __shared__ __align__(16) unsigned short Kt[64 * 72];      // [key][dim]
    __shared__ __align__(16) unsigned short Vt[64 * 72];      // [dim][key]
    __shared__ __align__(16) unsigned short Ps[4][16 * 72];   // per-wave P[q][k]

    const int qt = blockIdx.x;
    const int h  = blockIdx.y;
    const int n  = blockIdx.z;
    const int t0 = qt * 64;
    const int tid  = threadIdx.x;
    const int wave = tid >> 6;
    const int lane = tid & 63;
    const int l15  = lane & 15;
    const int lg   = lane >> 4;
    const int qrow = lg * 4;

    const unsigned short* qh  = qb + (size_t)(n * 8 + h) * 2048 * 64;
    const unsigned short* kh  = kb + (size_t)(n * 8 + h) * 2048 * 64;
    const unsigned short* vTh = vT + (size_t)(n * 8 + h) * 64 * 2048;

    bf16x8 qfrag[2];
    {
        const unsigned short* qp = qh + (size_t)(t0 + wave * 16 + l15) * 64;
        qfrag[0] = ld_frag(qp + lg * 8);
        qfrag[1] = ld_frag(qp + 32 + lg * 8);
    }

    const int skey = tid >> 2;            // K: key row   | V: dim row
    const int sd0  = (tid & 3) * 16;      // K: dim chunk | V: key chunk

    const int qq = wave * 16 + l15;       // this thread's query (within 64-tile)
    float m_v = -1e30f, l_v = 0.f;
    f32x4 acc_o[4] = {};

    for (int dt = -2; dt <= 2; ++dt) {
        const int kt = qt + dt;
        if (kt < 0 || kt > 31) continue;
        const int s0 = kt * 64;

        {   // stage K (compact rows) + V (pre-transposed vT) — coalesced
            const unsigned short* kp = kh + (size_t)(s0 + skey) * 64 + sd0;
            *(uint4*)&Kt[skey * 72 + sd0]     = *(const uint4*)kp;
            *(uint4*)&Kt[skey * 72 + sd0 + 8] = *(const uint4*)(kp + 8);

            const unsigned short* vp = vTh + (size_t)skey * 2048 + s0 + sd0;
            *(uint4*)&Vt[skey * 72 + sd0]     = *(const uint4*)vp;
            *(uint4*)&Vt[skey * 72 + sd0 + 8] = *(const uint4*)(vp + 8);
        }
        __syncthreads();

        // ---- S^T = K Q^T (skip fully-masked edge sub-tiles) ----
        f32x4 acc_s[4] = {};
        #pragma unroll
        for (int kstep = 0; kstep < 2; ++kstep) {
            #pragma unroll
            for (int nt = 0; nt < 4; ++nt) {
                if ((dt == -2 && nt < wave) || (dt == 2 && nt > wave)) continue;
                bf16x8 kf = ld_frag(&Kt[(nt * 16 + l15) * 72 + kstep * 32 + lg * 8]);
                acc_s[nt] = __builtin_amdgcn_mfma_f32_16x16x32_bf16(
                    kf, qfrag[kstep], acc_s[nt], 0, 0, 0);
            }
        }

        // ---- per-thread softmax over 16 scores (one query = l15) ----
        float p[4][4];
        float tm = -1e30f;
        #pragma unroll
        for (int nt = 0; nt < 4; ++nt) {
            #pragma unroll
            for (int r = 0; r < 4; ++r) {
                const int diff = dt * 64 + nt * 16 + qrow + r - qq;
                const bool ok = (diff >= -127) && (diff <= 128);
                const float v = ok ? acc_s[nt][r] : -1e30f;   // scale folded in q
                p[nt][r] = v;
                tm = fmaxf(tm, v);
            }
        }
        tm = fmaxf(tm, __shfl_xor(tm, 16, 64));
        tm = fmaxf(tm, __shfl_xor(tm, 32, 64));
        const float m_new = fmaxf(m_v, tm);
        const float alpha = __expf(m_v - m_new);
        float psum = 0.f;
        #pragma unroll
        for (int nt = 0; nt < 4; ++nt) {
            #pragma unroll
            for (int r = 0; r < 4; ++r) {
                const float e = __expf(p[nt][r] - m_new);
                p[nt][r] = e;
                psum += e;
            }
        }
        psum += __shfl_xor(psum, 16, 64);
        psum += __shfl_xor(psum, 32, 64);
        l_v = l_v * alpha + psum;
        m_v = m_new;

        // rescale acc_o: alpha for query lg*4+r lives in lane (lane&48)|(qrow+r)
        #pragma unroll
        for (int r = 0; r < 4; ++r) {
            const float a_r = __shfl(alpha, (lane & 48) + qrow + r, 64);
            #pragma unroll
            for (int nt = 0; nt < 4; ++nt) acc_o[nt][r] *= a_r;
        }

        // P -> Ps[q][k]: k = nt*16 + qrow + {0..3} contiguous -> packed 8B.
        // Wave-private: no barrier before the pfrag read (same-wave DS order).
        #pragma unroll
        for (int nt = 0; nt < 4; ++nt) {
            uint2 o;
            o.x = packbf2(p[nt][0], p[nt][1]);
            o.y = packbf2(p[nt][2], p[nt][3]);
            *(uint2*)&Ps[wave][l15 * 72 + nt * 16 + qrow] = o;
        }

        bf16x8 pfrag[2];
        pfrag[0] = ld_frag(&Ps[wave][l15 * 72 + lg * 8]);
        pfrag[1] = ld_frag(&Ps[wave][l15 * 72 + 32 + lg * 8]);

        #pragma unroll
        for (int kstep = 0; kstep < 2; ++kstep) {
            #pragma unroll
            for (int nt = 0; nt < 4; ++nt) {
                bf16x8 vf = ld_frag(&Vt[(nt * 16 + l15) * 72 + kstep * 32 + lg * 8]);
                acc_o[nt] = __builtin_amdgcn_mfma_f32_16x16x32_bf16(
                    pfrag[kstep], vf, acc_o[nt], 0, 0, 0);
            }
        }
        __syncthreads();   // all waves done reading Kt/Vt before next stage
    }

    // 1/l for query lg*4+r lives in lane (lane&48)|(qrow+r)
    const float linv = 1.0f / l_v;
    float inv_l[4];
    #pragma unroll
    for (int r = 0; r < 4; ++r)
        inv_l[r] = __shfl(linv, (lane & 48) + qrow + r, 64);

    #pragma unroll
    for (int r = 0; r < 4; ++r) {
        const int tq = t0 + wave * 16 + qrow + r;
        unsigned short* op = attnout + (size_t)(n * 2048 + tq) * 512 + h * 64;
        #pragma unroll
        for (int nt = 0; nt < 4; ++nt)
            op[nt * 16 + l15] = f2bf(acc_o[nt][r] * inv_l[r]);
    }
}

extern "C" void kernel_launch(void* const* d_in, const int* in_sizes, int n_in,
                              void* d_out, int out_size, void* d_ws, size_t ws_size,
                              hipStream_t stream)
{
    (void)in_sizes; (void)n_in; (void)out_size; (void)ws_size;

    const float* x     = (const float*)d_in[0];
    const float* Wqkv  = (const float*)d_in[1];
    const float* out_w = (const float*)d_in[2];
    const float* out_b = (const float*)d_in[3];
    float* out = (float*)d_out;

    unsigned short* qb    = (unsigned short*)d_ws;          // 4*8*2048*64 bf16
    unsigned short* kbuf  = qb + (size_t)4 * 8 * 2048 * 64; // 4*8*2048*64 bf16
    unsigned short* vTb   = kbuf + (size_t)4 * 8 * 2048 * 64; // 4*8*64*2048
    unsigned short* attnb = vTb + (size_t)4 * 8 * 64 * 2048;  // 8192*512 bf16
    unsigned short* xb    = attnb + (size_t)8192 * 512;     // 8192*512  bf16
    unsigned short* wqkvb = xb + (size_t)8192 * 512;        // 1536*512  bf16
    unsigned short* outwb = wqkvb + (size_t)1536 * 512;     // 512*512   bf16

    // 0) all fp32->bf16 conversions in one launch
    cvt_all<<<5120, 256, 0, stream>>>(x, Wqkv, out_w, xb, wqkvb, outwb);

    // 1) qkv = x @ Wqkv^T with fused RoPE + q-scale -> compact qb/kb + vT
    gemm_bt_mfma<<<dim3(64, 24), 256, 0, stream>>>(xb, wqkvb, nullptr, nullptr,
                                                   8192, 1536, 512, 1, 1,
                                                   vTb, qb, kbuf);
    // 2) flash attention -> attnb bf16
    attn_mfma_kernel<<<dim3(32, 8, 4), 256, 0, stream>>>(qb, kbuf, vTb, attnb);
    // 3) out = attn @ out_w^T + out_b (fp32 out)
    gemm_bt_mfma<<<dim3(64, 8), 256, 0, stream>>>(attnb, outwb, out_b, out,
                                                  8192, 512, 512, 0, 0,
                                                  nullptr, nullptr, nullptr);
}

// Round 12
// 126.270 us; speedup vs baseline: 1.2331x; 1.0122x over previous
//
#include <hip/hip_runtime.h>
#include <math.h>

// ---------------------------------------------------------------------------
// N=4, T=2048, D_MODEL=512, NHEAD=8, HEAD_DIM=64, window -127..+128.
// Pipeline: cvt_all -> bf16 ; qkv GEMM (MFMA, LDS-staged BM=128 BN=64 BK=64,
// XOR-swizzled, global_load_lds) + fused RoPE + q-scale -> compact qb/kb/vT ;
// flash attn (R19 loop, swapped-QK^T in-register softmax) ; out GEMM.
// R25: attn LDS shrink for occupancy: Kt/Vt [64][72] -> [64][64] with XOR
// chunk swizzle (16B chunk c of row r lives at slot c^(r&7); reads XOR
// (l15&7)). Bank profile PROVABLY identical to the padded-72 layout (8 lanes
// per 4-bank group either way) — change is purely LDS 27.6->25.2KB, i.e.
// 5 -> 6 blocks/CU, enforced by __launch_bounds__(256,6) (VGPR cap 85).
// Staging stays reg-based (R22 lesson: gload_lds vmcnt drain was the
// regression, not banks). MFMA inputs bitwise identical -> absmax must stay
// 0.0004882812.
// R24: compact qb/kb[nh][t][64] + vT[nh][d][t] layouts (neutral, kept —
// coalesced staging). R19: Ps needs no barrier (wave-private). R17: swapped
// QK^T in-reg softmax. R18: GEMM schedule frozen at BN=64/BK=64/(256,5).
// R15/R20: occupancy is the sticky optimum — this round raises it.
// ---------------------------------------------------------------------------

typedef __attribute__((ext_vector_type(8))) __bf16 bf16x8;
typedef __attribute__((ext_vector_type(4))) float f32x4;

__device__ __forceinline__ unsigned short f2bf(float f) {
    unsigned int u = __float_as_uint(f);
    u += 0x7fffu + ((u >> 16) & 1u);
    return (unsigned short)(u >> 16);
}
__device__ __forceinline__ unsigned int packbf2(float a, float b) {
    unsigned int ua = __float_as_uint(a); ua += 0x7fffu + ((ua >> 16) & 1u);
    unsigned int ub = __float_as_uint(b); ub += 0x7fffu + ((ub >> 16) & 1u);
    return (ua >> 16) | (ub & 0xffff0000u);
}
__device__ __forceinline__ bf16x8 as_bf16x8(uint4 u) {
    union { uint4 u4; bf16x8 v; } c; c.u4 = u; return c.v;
}
__device__ __forceinline__ bf16x8 ld_frag(const unsigned short* p) {
    return as_bf16x8(*(const uint4*)p);
}

__device__ __forceinline__ void async16(void* lds, const void* g) {
    __builtin_amdgcn_global_load_lds(
        (const __attribute__((address_space(1))) void*)g,
        (__attribute__((address_space(3))) void*)lds,
        16, 0, 0);
}

// One kernel converts all three fp32 inputs to bf16 (4 elems/thread).
__global__ __launch_bounds__(256) void cvt_all(
    const float* __restrict__ x, const float* __restrict__ w1,
    const float* __restrict__ w2,
    unsigned short* __restrict__ xb, unsigned short* __restrict__ w1b,
    unsigned short* __restrict__ w2b)
{
    const int n_x  = 8192 * 512 / 4;
    const int n_w1 = 1536 * 512 / 4;
    const int n_w2 = 512 * 512 / 4;
    int i = blockIdx.x * 256 + threadIdx.x;
    const float* in; unsigned short* out; int j;
    if (i < n_x)                    { in = x;  out = xb;  j = i; }
    else if (i < n_x + n_w1)        { in = w1; out = w1b; j = i - n_x; }
    else if (i < n_x + n_w1 + n_w2) { in = w2; out = w2b; j = i - n_x - n_w1; }
    else return;
    float4 v = *(const float4*)(in + 4 * (size_t)j);
    uint2 o;
    o.x = packbf2(v.x, v.y);
    o.y = packbf2(v.z, v.w);
    *(uint2*)(out + 4 * (size_t)j) = o;
}

// C[M,O] = A[M,K](bf16) * B[O,K](bf16)^T (+bias). Output fp32 or bf16.
// BM=128, BN=64, BK=64. Block=256 (4 waves); wave w computes rows
// [w*32,+32) x all 64 cols (mt=2, nt=4; acc 32 AGPR).
// __launch_bounds__(256,5): 5 blocks/CU. Schedule frozen (R15/R18).
// do_rope (qkv layout, O=1536): RoPE cols<1024, fold 1/8 into q cols<512.
// Writes route to COMPACT buffers: cols<512 -> qb[n*8+h][t][64];
// 512..1024 -> kb (same layout); >=1024 -> vT[n*8+h][dim][t] transposed.
__global__ __launch_bounds__(256, 5) void gemm_bt_mfma(
    const unsigned short* __restrict__ A, const unsigned short* __restrict__ B,
    const float* __restrict__ bias, void* __restrict__ Cout,
    int M, int O, int K, int write_bf16, int do_rope,
    unsigned short* __restrict__ vT,
    unsigned short* __restrict__ qbuf, unsigned short* __restrict__ kbuf)
{
    __shared__ __align__(16) unsigned short As[128 * 64];   // 16 KB
    __shared__ __align__(16) unsigned short Bs[64 * 64];    // 8 KB

    const int tid  = threadIdx.x;
    const int wave = tid >> 6;
    const int lane = tid & 63;
    const int l15  = lane & 15;
    const int lg   = lane >> 4;
    const int row0 = blockIdx.x * 128;
    const int col0 = blockIdx.y * 64;
    const int wr   = wave * 32;

    f32x4 acc[2][4] = {};

    const int srow = tid >> 3;
    const int skg  = ((tid & 7) * 8) ^ ((srow & 7) * 8);
    const int fx   = (l15 & 7) * 8;

    for (int k0 = 0; k0 < K; k0 += 64) {
        #pragma unroll
        for (int s = 0; s < 4; ++s)
            async16(&As[(size_t)(s * 256 + tid) * 8],
                    A + (size_t)(row0 + s * 32 + srow) * K + k0 + skg);
        #pragma unroll
        for (int s = 0; s < 2; ++s)
            async16(&Bs[(size_t)(s * 256 + tid) * 8],
                    B + (size_t)(col0 + s * 32 + srow) * K + k0 + skg);
        __syncthreads();

        #pragma unroll
        for (int kstep = 0; kstep < 2; ++kstep) {
            const int kq = (kstep * 32 + lg * 8) ^ fx;
            bf16x8 af[2], bfr[4];
            #pragma unroll
            for (int mt = 0; mt < 2; ++mt)
                af[mt] = ld_frag(&As[(wr + mt * 16 + l15) * 64 + kq]);
            #pragma unroll
            for (int nt = 0; nt < 4; ++nt)
                bfr[nt] = ld_frag(&Bs[(nt * 16 + l15) * 64 + kq]);
            #pragma unroll
            for (int mt = 0; mt < 2; ++mt)
                #pragma unroll
                for (int nt = 0; nt < 4; ++nt)
                    acc[mt][nt] = __builtin_amdgcn_mfma_f32_16x16x32_bf16(
                        af[mt], bfr[nt], acc[mt][nt], 0, 0, 0);
        }
        __syncthreads();
    }

    const int qrow = lg * 4;

    if (do_rope) {
        if (col0 < 1024) {
            const float cfreq = 0.28782313662425574f;   // ln(10000)/32
            const float invf0 = __expf(-(float)l15 * cfreq);
            const float invf1 = __expf(-(float)(16 + l15) * cfreq);
            #pragma unroll
            for (int mt = 0; mt < 2; ++mt) {
                #pragma unroll
                for (int r = 0; r < 4; ++r) {
                    const int t = (row0 + wr + mt * 16 + qrow + r) & 2047;
                    #pragma unroll
                    for (int p = 0; p < 2; ++p) {
                        float ang = (float)t * (p ? invf1 : invf0);
                        float s, c;
                        __sincosf(ang, &s, &c);
                        float a = acc[mt][p][r];       // d = p*16+l15 (< 32)
                        float b = acc[mt][p + 2][r];   // d = 32 + p*16+l15
                        acc[mt][p][r]     = a * c - b * s;
                        acc[mt][p + 2][r] = b * c + a * s;
                    }
                }
            }
            if (col0 < 512) {   // q: fold softmax scale 1/sqrt(64)
                #pragma unroll
                for (int mt = 0; mt < 2; ++mt)
                    #pragma unroll
                    for (int nt = 0; nt < 4; ++nt)
                        #pragma unroll
                        for (int r = 0; r < 4; ++r)
                            acc[mt][nt][r] *= 0.125f;
            }
            // write COMPACT qb/kb[nh][t][64]
            unsigned short* dst = (col0 < 512) ? qbuf : kbuf;
            const int cbase = (col0 < 512) ? col0 : col0 - 512;
            #pragma unroll
            for (int nt = 0; nt < 4; ++nt) {
                const int local = cbase + nt * 16 + l15;
                const int hh = local >> 6;
                const int dd = local & 63;
                #pragma unroll
                for (int mt = 0; mt < 2; ++mt) {
                    const int rowb = row0 + wr + mt * 16 + qrow;
                    const int nn = rowb >> 11;
                    const int tt = rowb & 2047;
                    unsigned short* p = dst +
                        ((size_t)(nn * 8 + hh) * 2048 + tt) * 64 + dd;
                    #pragma unroll
                    for (int r = 0; r < 4; ++r)
                        p[(size_t)r * 64] = f2bf(acc[mt][nt][r]);
                }
            }
        } else {
            // V columns: write transposed into vT[nh][dim][t] (bf16).
            #pragma unroll
            for (int nt = 0; nt < 4; ++nt) {
                const int local = col0 - 1024 + nt * 16 + l15;
                const int hh = local >> 6;
                const int dd = local & 63;
                #pragma unroll
                for (int mt = 0; mt < 2; ++mt) {
                    const int rowb = row0 + wr + mt * 16 + qrow;
                    const int nn = rowb >> 11;
                    const int tt = rowb & 2047;
                    uint2 o;
                    o.x = packbf2(acc[mt][nt][0], acc[mt][nt][1]);
                    o.y = packbf2(acc[mt][nt][2], acc[mt][nt][3]);
                    *(uint2*)(vT + ((size_t)(nn * 8 + hh) * 64 + dd) * 2048 + tt) = o;
                }
            }
        }
        return;
    }

    #pragma unroll
    for (int nt = 0; nt < 4; ++nt) {
        const int col = col0 + nt * 16 + l15;
        const float bv = bias ? bias[col] : 0.f;
        #pragma unroll
        for (int mt = 0; mt < 2; ++mt) {
            const int rowb = row0 + wr + mt * 16 + qrow;
            if (write_bf16) {
                unsigned short* C = (unsigned short*)Cout;
                #pragma unroll
                for (int r = 0; r < 4; ++r)
                    C[(size_t)(rowb + r) * O + col] = f2bf(acc[mt][nt][r] + bv);
            } else {
                float* C = (float*)Cout;
                #pragma unroll
                for (int r = 0; r < 4; ++r)
                    C[(size_t)(rowb + r) * O + col] = acc[mt][nt][r] + bv;
            }
        }
    }
}

// Flash attention with MFMA. Block=256 (4 waves) handles (qt, h, n).
// R25: Kt/Vt are UNPADDED [64][64] with 16B-chunk XOR swizzle — chunk c of
// row r lives at slot c^(r&7); reads use slot (kstep*4+lg)^(l15&7). Bank
// profile identical to the old padded-72 layout; LDS 27.6->25.2KB unlocks
// 6 blocks/CU (launch_bounds(256,6), VGPR cap 85). Staging reg-based
// (R14/R24 form), coalesced from compact kb / vT. 2 barriers/tile (R19).
// R17: swapped QK^T — acc_s = mfma(kf, qfrag) computes S^T: row=key
// (nt*16+lg*4+r), col=query (l15). Thread owns ONE query, 16 scores in regs;
// softmax = in-reg max/sum + 2 shfl_xor; P written as 4x packed ds_write_b64
// into Ps[q][k] (72-padded: b128 reads need the bank spread there); alpha
// and 1/l redistributed to PV layout via shfl. Fully-masked-tile semantics
// preserved. q pre-scaled by 1/8 in the QKV GEMM.
__global__ __launch_bounds__(256, 6) void attn_mfma_kernel(
    const unsigned short* __restrict__ qb,
    const unsigned short* __restrict__ kb,
    const unsigned short* __restrict__ vT,
    unsigned short* __restrict__ attnout)
{
    __shared__ __align__(16) unsigned short Kt[64 * 64];      // 8 KB swizzled
    __shared__ __align__(16) unsigned short Vt[64 * 64];      // 8 KB swizzled
    __shared__ __align__(16) unsigned short Ps[4][16 * 72];   // 9.2 KB

    const int qt = blockIdx.x;
    const int h  = blockIdx.y;
    const int n  = blockIdx.z;
    const int t0 = qt * 64;
    const int tid  = threadIdx.x;
    const int wave = tid >> 6;
    const int lane = tid & 63;
    const int l15  = lane & 15;
    const int lg   = lane >> 4;
    const int qrow = lg * 4;

    const unsigned short* qh  = qb + (size_t)(n * 8 + h) * 2048 * 64;
    const unsigned short* kh  = kb + (size_t)(n * 8 + h) * 2048 * 64;
    const unsigned short* vTh = vT + (size_t)(n * 8 + h) * 64 * 2048;

    bf16x8 qfrag[2];
    {
        const unsigned short* qp = qh + (size_t)(t0 + wave * 16 + l15) * 64;
        qfrag[0] = ld_frag(qp + lg * 8);
        qfrag[1] = ld_frag(qp + 32 + lg * 8);
    }

    const int skey = tid >> 2;            // row 0..63 (K: key | V: dim)
    const int c0   = (tid & 3) * 2;       // first of two 16B chunks
    const int sw0  = (c0 ^ (skey & 7)) * 8;        // swizzled slot, chunk c0
    const int sw1  = ((c0 + 1) ^ (skey & 7)) * 8;  // swizzled slot, chunk c0+1
    const int kx   = l15 & 7;             // read-side chunk XOR

    const int qq = wave * 16 + l15;       // this thread's query (within 64-tile)
    float m_v = -1e30f, l_v = 0.f;
    f32x4 acc_o[4] = {};

    for (int dt = -2; dt <= 2; ++dt) {
        const int kt = qt + dt;
        if (kt < 0 || kt > 31) continue;
        const int s0 = kt * 64;

        {   // stage K + V (reg-based, coalesced), swizzled chunk slots
            const unsigned short* kp = kh + (size_t)(s0 + skey) * 64 + c0 * 8;
            *(uint4*)&Kt[skey * 64 + sw0] = *(const uint4*)kp;
            *(uint4*)&Kt[skey * 64 + sw1] = *(const uint4*)(kp + 8);

            const unsigned short* vp = vTh + (size_t)skey * 2048 + s0 + c0 * 8;
            *(uint4*)&Vt[skey * 64 + sw0] = *(const uint4*)vp;
            *(uint4*)&Vt[skey * 64 + sw1] = *(const uint4*)(vp + 8);
        }
        __syncthreads();

        // ---- S^T = K Q^T (skip fully-masked edge sub-tiles) ----
        f32x4 acc_s[4] = {};
        #pragma unroll
        for (int kstep = 0; kstep < 2; ++kstep) {
            #pragma unroll
            for (int nt = 0; nt < 4; ++nt) {
                if ((dt == -2 && nt < wave) || (dt == 2 && nt > wave)) continue;
                bf16x8 kf = ld_frag(&Kt[(nt * 16 + l15) * 64 +
                                        ((kstep * 4 + lg) ^ kx) * 8]);
                acc_s[nt] = __builtin_amdgcn_mfma_f32_16x16x32_bf16(
                    kf, qfrag[kstep], acc_s[nt], 0, 0, 0);
            }
        }

        // ---- per-thread softmax over 16 scores (one query = l15) ----
        float p[4][4];
        float tm = -1e30f;
        #pragma unroll
        for (int nt = 0; nt < 4; ++nt) {
            #pragma unroll
            for (int r = 0; r < 4; ++r) {
                const int diff = dt * 64 + nt * 16 + qrow + r - qq;
                const bool ok = (diff >= -127) && (diff <= 128);
                const float v = ok ? acc_s[nt][r] : -1e30f;   // scale folded in q
                p[nt][r] = v;
                tm = fmaxf(tm, v);
            }
        }
        tm = fmaxf(tm, __shfl_xor(tm, 16, 64));
        tm = fmaxf(tm, __shfl_xor(tm, 32, 64));
        const float m_new = fmaxf(m_v, tm);
        const float alpha = __expf(m_v - m_new);
        float psum = 0.f;
        #pragma unroll
        for (int nt = 0; nt < 4; ++nt) {
            #pragma unroll
            for (int r = 0; r < 4; ++r) {
                const float e = __expf(p[nt][r] - m_new);
                p[nt][r] = e;
                psum += e;
            }
        }
        psum += __shfl_xor(psum, 16, 64);
        psum += __shfl_xor(psum, 32, 64);
        l_v = l_v * alpha + psum;
        m_v = m_new;

        // rescale acc_o: alpha for query lg*4+r lives in lane (lane&48)|(qrow+r)
        #pragma unroll
        for (int r = 0; r < 4; ++r) {
            const float a_r = __shfl(alpha, (lane & 48) + qrow + r, 64);
            #pragma unroll
            for (int nt = 0; nt < 4; ++nt) acc_o[nt][r] *= a_r;
        }

        // P -> Ps[q][k]: k = nt*16 + qrow + {0..3} contiguous -> packed 8B.
        // Wave-private: no barrier before the pfrag read (same-wave DS order).
        #pragma unroll
        for (int nt = 0; nt < 4; ++nt) {
            uint2 o;
            o.x = packbf2(p[nt][0], p[nt][1]);
            o.y = packbf2(p[nt][2], p[nt][3]);
            *(uint2*)&Ps[wave][l15 * 72 + nt * 16 + qrow] = o;
        }

        bf16x8 pfrag[2];
        pfrag[0] = ld_frag(&Ps[wave][l15 * 72 + lg * 8]);
        pfrag[1] = ld_frag(&Ps[wave][l15 * 72 + 32 + lg * 8]);

        #pragma unroll
        for (int kstep = 0; kstep < 2; ++kstep) {
            #pragma unroll
            for (int nt = 0; nt < 4; ++nt) {
                bf16x8 vf = ld_frag(&Vt[(nt * 16 + l15) * 64 +
                                        ((kstep * 4 + lg) ^ kx) * 8]);
                acc_o[nt] = __builtin_amdgcn_mfma_f32_16x16x32_bf16(
                    pfrag[kstep], vf, acc_o[nt], 0, 0, 0);
            }
        }
        __syncthreads();   // all waves done reading Kt/Vt before next stage
    }

    // 1/l for query lg*4+r lives in lane (lane&48)|(qrow+r)
    const float linv = 1.0f / l_v;
    float inv_l[4];
    #pragma unroll
    for (int r = 0; r < 4; ++r)
        inv_l[r] = __shfl(linv, (lane & 48) + qrow + r, 64);

    #pragma unroll
    for (int r = 0; r < 4; ++r) {
        const int tq = t0 + wave * 16 + qrow + r;
        unsigned short* op = attnout + (size_t)(n * 2048 + tq) * 512 + h * 64;
        #pragma unroll
        for (int nt = 0; nt < 4; ++nt)
            op[nt * 16 + l15] = f2bf(acc_o[nt][r] * inv_l[r]);
    }
}

extern "C" void kernel_launch(void* const* d_in, const int* in_sizes, int n_in,
                              void* d_out, int out_size, void* d_ws, size_t ws_size,
                              hipStream_t stream)
{
    (void)in_sizes; (void)n_in; (void)out_size; (void)ws_size;

    const float* x     = (const float*)d_in[0];
    const float* Wqkv  = (const float*)d_in[1];
    const float* out_w = (const float*)d_in[2];
    const float* out_b = (const float*)d_in[3];
    float* out = (float*)d_out;

    unsigned short* qb    = (unsigned short*)d_ws;          // 4*8*2048*64 bf16
    unsigned short* kbuf  = qb + (size_t)4 * 8 * 2048 * 64; // 4*8*2048*64 bf16
    unsigned short* vTb   = kbuf + (size_t)4 * 8 * 2048 * 64; // 4*8*64*2048
    unsigned short* attnb = vTb + (size_t)4 * 8 * 64 * 2048;  // 8192*512 bf16
    unsigned short* xb    = attnb + (size_t)8192 * 512;     // 8192*512  bf16
    unsigned short* wqkvb = xb + (size_t)8192 * 512;        // 1536*512  bf16
    unsigned short* outwb = wqkvb + (size_t)1536 * 512;     // 512*512   bf16

    // 0) all fp32->bf16 conversions in one launch
    cvt_all<<<5120, 256, 0, stream>>>(x, Wqkv, out_w, xb, wqkvb, outwb);

    // 1) qkv = x @ Wqkv^T with fused RoPE + q-scale -> compact qb/kb + vT
    gemm_bt_mfma<<<dim3(64, 24), 256, 0, stream>>>(xb, wqkvb, nullptr, nullptr,
                                                   8192, 1536, 512, 1, 1,
                                                   vTb, qb, kbuf);
    // 2) flash attention -> attnb bf16
    attn_mfma_kernel<<<dim3(32, 8, 4), 256, 0, stream>>>(qb, kbuf, vTb, attnb);
    // 3) out = attn @ out_w^T + out_b (fp32 out)
    gemm_bt_mfma<<<dim3(64, 8), 256, 0, stream>>>(attnb, outwb, out_b, out,
                                                  8192, 512, 512, 0, 0,
                                                  nullptr, nullptr, nullptr);
}

// Round 13
// 124.463 us; speedup vs baseline: 1.2510x; 1.0145x over previous
//
#include <hip/hip_runtime.h>
#include <math.h>

// ---------------------------------------------------------------------------
// N=4, T=2048, D_MODEL=512, NHEAD=8, HEAD_DIM=64, window -127..+128.
// Pipeline: cvt_all -> bf16 ; qkv GEMM (MFMA, LDS-staged BM=128 BN=64 BK=64,
// XOR-swizzled, global_load_lds) + fused RoPE + q-scale -> compact qb/kb/vT ;
// flash attn (R19 loop, swapped-QK^T in-register softmax) ; out GEMM.
// R26: GEMM __launch_bounds__ (256,5) -> (256,6): LDS (24KB) permits 6
// blocks/CU; the 102-reg cap of (256,5) was the binder. k-loop working set
// ~76 VGPR fits the 85-reg cap of (256,6); RoPE epilogue spills (if any) are
// once-per-block. Third application of the session's one proven lever
// (occupancy): R25 attn 5->6 won, R15/R18/R20 losing it regressed.
// R25: attn Kt/Vt unpadded [64][64] + XOR chunk swizzle, 6 blocks/CU (won).
// R24: compact qb/kb[nh][t][64] + vT[nh][d][t] layouts (kept).
// R19: Ps needs no barrier (wave-private). R17: swapped QK^T in-reg softmax.
// R18: GEMM inner schedule frozen at BN=64/BK=64. R15/R20: occupancy rules.
// ---------------------------------------------------------------------------

typedef __attribute__((ext_vector_type(8))) __bf16 bf16x8;
typedef __attribute__((ext_vector_type(4))) float f32x4;

__device__ __forceinline__ unsigned short f2bf(float f) {
    unsigned int u = __float_as_uint(f);
    u += 0x7fffu + ((u >> 16) & 1u);
    return (unsigned short)(u >> 16);
}
__device__ __forceinline__ unsigned int packbf2(float a, float b) {
    unsigned int ua = __float_as_uint(a); ua += 0x7fffu + ((ua >> 16) & 1u);
    unsigned int ub = __float_as_uint(b); ub += 0x7fffu + ((ub >> 16) & 1u);
    return (ua >> 16) | (ub & 0xffff0000u);
}
__device__ __forceinline__ bf16x8 as_bf16x8(uint4 u) {
    union { uint4 u4; bf16x8 v; } c; c.u4 = u; return c.v;
}
__device__ __forceinline__ bf16x8 ld_frag(const unsigned short* p) {
    return as_bf16x8(*(const uint4*)p);
}

__device__ __forceinline__ void async16(void* lds, const void* g) {
    __builtin_amdgcn_global_load_lds(
        (const __attribute__((address_space(1))) void*)g,
        (__attribute__((address_space(3))) void*)lds,
        16, 0, 0);
}

// One kernel converts all three fp32 inputs to bf16 (4 elems/thread).
__global__ __launch_bounds__(256) void cvt_all(
    const float* __restrict__ x, const float* __restrict__ w1,
    const float* __restrict__ w2,
    unsigned short* __restrict__ xb, unsigned short* __restrict__ w1b,
    unsigned short* __restrict__ w2b)
{
    const int n_x  = 8192 * 512 / 4;
    const int n_w1 = 1536 * 512 / 4;
    const int n_w2 = 512 * 512 / 4;
    int i = blockIdx.x * 256 + threadIdx.x;
    const float* in; unsigned short* out; int j;
    if (i < n_x)                    { in = x;  out = xb;  j = i; }
    else if (i < n_x + n_w1)        { in = w1; out = w1b; j = i - n_x; }
    else if (i < n_x + n_w1 + n_w2) { in = w2; out = w2b; j = i - n_x - n_w1; }
    else return;
    float4 v = *(const float4*)(in + 4 * (size_t)j);
    uint2 o;
    o.x = packbf2(v.x, v.y);
    o.y = packbf2(v.z, v.w);
    *(uint2*)(out + 4 * (size_t)j) = o;
}

// C[M,O] = A[M,K](bf16) * B[O,K](bf16)^T (+bias). Output fp32 or bf16.
// BM=128, BN=64, BK=64. Block=256 (4 waves); wave w computes rows
// [w*32,+32) x all 64 cols (mt=2, nt=4; acc 32 AGPR).
// R26: __launch_bounds__(256,6) — LDS allows 6 blocks/CU (24KB); the former
// (256,5) 102-reg cap was the binder. k-loop working set ~76 VGPR < 85 cap.
// do_rope (qkv layout, O=1536): RoPE cols<1024, fold 1/8 into q cols<512.
// Writes route to COMPACT buffers: cols<512 -> qb[n*8+h][t][64];
// 512..1024 -> kb (same layout); >=1024 -> vT[n*8+h][dim][t] transposed.
__global__ __launch_bounds__(256, 6) void gemm_bt_mfma(
    const unsigned short* __restrict__ A, const unsigned short* __restrict__ B,
    const float* __restrict__ bias, void* __restrict__ Cout,
    int M, int O, int K, int write_bf16, int do_rope,
    unsigned short* __restrict__ vT,
    unsigned short* __restrict__ qbuf, unsigned short* __restrict__ kbuf)
{
    __shared__ __align__(16) unsigned short As[128 * 64];   // 16 KB
    __shared__ __align__(16) unsigned short Bs[64 * 64];    // 8 KB

    const int tid  = threadIdx.x;
    const int wave = tid >> 6;
    const int lane = tid & 63;
    const int l15  = lane & 15;
    const int lg   = lane >> 4;
    const int row0 = blockIdx.x * 128;
    const int col0 = blockIdx.y * 64;
    const int wr   = wave * 32;

    f32x4 acc[2][4] = {};

    const int srow = tid >> 3;
    const int skg  = ((tid & 7) * 8) ^ ((srow & 7) * 8);
    const int fx   = (l15 & 7) * 8;

    for (int k0 = 0; k0 < K; k0 += 64) {
        #pragma unroll
        for (int s = 0; s < 4; ++s)
            async16(&As[(size_t)(s * 256 + tid) * 8],
                    A + (size_t)(row0 + s * 32 + srow) * K + k0 + skg);
        #pragma unroll
        for (int s = 0; s < 2; ++s)
            async16(&Bs[(size_t)(s * 256 + tid) * 8],
                    B + (size_t)(col0 + s * 32 + srow) * K + k0 + skg);
        __syncthreads();

        #pragma unroll
        for (int kstep = 0; kstep < 2; ++kstep) {
            const int kq = (kstep * 32 + lg * 8) ^ fx;
            bf16x8 af[2], bfr[4];
            #pragma unroll
            for (int mt = 0; mt < 2; ++mt)
                af[mt] = ld_frag(&As[(wr + mt * 16 + l15) * 64 + kq]);
            #pragma unroll
            for (int nt = 0; nt < 4; ++nt)
                bfr[nt] = ld_frag(&Bs[(nt * 16 + l15) * 64 + kq]);
            #pragma unroll
            for (int mt = 0; mt < 2; ++mt)
                #pragma unroll
                for (int nt = 0; nt < 4; ++nt)
                    acc[mt][nt] = __builtin_amdgcn_mfma_f32_16x16x32_bf16(
                        af[mt], bfr[nt], acc[mt][nt], 0, 0, 0);
        }
        __syncthreads();
    }

    const int qrow = lg * 4;

    if (do_rope) {
        if (col0 < 1024) {
            const float cfreq = 0.28782313662425574f;   // ln(10000)/32
            const float invf0 = __expf(-(float)l15 * cfreq);
            const float invf1 = __expf(-(float)(16 + l15) * cfreq);
            #pragma unroll
            for (int mt = 0; mt < 2; ++mt) {
                #pragma unroll
                for (int r = 0; r < 4; ++r) {
                    const int t = (row0 + wr + mt * 16 + qrow + r) & 2047;
                    #pragma unroll
                    for (int p = 0; p < 2; ++p) {
                        float ang = (float)t * (p ? invf1 : invf0);
                        float s, c;
                        __sincosf(ang, &s, &c);
                        float a = acc[mt][p][r];       // d = p*16+l15 (< 32)
                        float b = acc[mt][p + 2][r];   // d = 32 + p*16+l15
                        acc[mt][p][r]     = a * c - b * s;
                        acc[mt][p + 2][r] = b * c + a * s;
                    }
                }
            }
            if (col0 < 512) {   // q: fold softmax scale 1/sqrt(64)
                #pragma unroll
                for (int mt = 0; mt < 2; ++mt)
                    #pragma unroll
                    for (int nt = 0; nt < 4; ++nt)
                        #pragma unroll
                        for (int r = 0; r < 4; ++r)
                            acc[mt][nt][r] *= 0.125f;
            }
            // write COMPACT qb/kb[nh][t][64]
            unsigned short* dst = (col0 < 512) ? qbuf : kbuf;
            const int cbase = (col0 < 512) ? col0 : col0 - 512;
            #pragma unroll
            for (int nt = 0; nt < 4; ++nt) {
                const int local = cbase + nt * 16 + l15;
                const int hh = local >> 6;
                const int dd = local & 63;
                #pragma unroll
                for (int mt = 0; mt < 2; ++mt) {
                    const int rowb = row0 + wr + mt * 16 + qrow;
                    const int nn = rowb >> 11;
                    const int tt = rowb & 2047;
                    unsigned short* p = dst +
                        ((size_t)(nn * 8 + hh) * 2048 + tt) * 64 + dd;
                    #pragma unroll
                    for (int r = 0; r < 4; ++r)
                        p[(size_t)r * 64] = f2bf(acc[mt][nt][r]);
                }
            }
        } else {
            // V columns: write transposed into vT[nh][dim][t] (bf16).
            #pragma unroll
            for (int nt = 0; nt < 4; ++nt) {
                const int local = col0 - 1024 + nt * 16 + l15;
                const int hh = local >> 6;
                const int dd = local & 63;
                #pragma unroll
                for (int mt = 0; mt < 2; ++mt) {
                    const int rowb = row0 + wr + mt * 16 + qrow;
                    const int nn = rowb >> 11;
                    const int tt = rowb & 2047;
                    uint2 o;
                    o.x = packbf2(acc[mt][nt][0], acc[mt][nt][1]);
                    o.y = packbf2(acc[mt][nt][2], acc[mt][nt][3]);
                    *(uint2*)(vT + ((size_t)(nn * 8 + hh) * 64 + dd) * 2048 + tt) = o;
                }
            }
        }
        return;
    }

    #pragma unroll
    for (int nt = 0; nt < 4; ++nt) {
        const int col = col0 + nt * 16 + l15;
        const float bv = bias ? bias[col] : 0.f;
        #pragma unroll
        for (int mt = 0; mt < 2; ++mt) {
            const int rowb = row0 + wr + mt * 16 + qrow;
            if (write_bf16) {
                unsigned short* C = (unsigned short*)Cout;
                #pragma unroll
                for (int r = 0; r < 4; ++r)
                    C[(size_t)(rowb + r) * O + col] = f2bf(acc[mt][nt][r] + bv);
            } else {
                float* C = (float*)Cout;
                #pragma unroll
                for (int r = 0; r < 4; ++r)
                    C[(size_t)(rowb + r) * O + col] = acc[mt][nt][r] + bv;
            }
        }
    }
}

// Flash attention with MFMA. Block=256 (4 waves) handles (qt, h, n).
// R25: Kt/Vt are UNPADDED [64][64] with 16B-chunk XOR swizzle — chunk c of
// row r lives at slot c^(r&7); reads use slot (kstep*4+lg)^(l15&7). Bank
// profile identical to the old padded-72 layout; LDS 27.6->25.2KB unlocks
// 6 blocks/CU (launch_bounds(256,6), VGPR cap 85). Staging reg-based,
// coalesced from compact kb / vT. 2 barriers/tile (R19).
// R17: swapped QK^T — acc_s = mfma(kf, qfrag) computes S^T: row=key
// (nt*16+lg*4+r), col=query (l15). Thread owns ONE query, 16 scores in regs;
// softmax = in-reg max/sum + 2 shfl_xor; P written as 4x packed ds_write_b64
// into Ps[q][k]; alpha and 1/l redistributed to PV layout via shfl.
// Fully-masked-tile semantics preserved. q pre-scaled by 1/8 in the QKV GEMM.
__global__ __launch_bounds__(256, 6) void attn_mfma_kernel(
    const unsigned short* __restrict__ qb,
    const unsigned short* __restrict__ kb,
    const unsigned short* __restrict__ vT,
    unsigned short* __restrict__ attnout)
{
    __shared__ __align__(16) unsigned short Kt[64 * 64];      // 8 KB swizzled
    __shared__ __align__(16) unsigned short Vt[64 * 64];      // 8 KB swizzled
    __shared__ __align__(16) unsigned short Ps[4][16 * 72];   // 9.2 KB

    const int qt = blockIdx.x;
    const int h  = blockIdx.y;
    const int n  = blockIdx.z;
    const int t0 = qt * 64;
    const int tid  = threadIdx.x;
    const int wave = tid >> 6;
    const int lane = tid & 63;
    const int l15  = lane & 15;
    const int lg   = lane >> 4;
    const int qrow = lg * 4;

    const unsigned short* qh  = qb + (size_t)(n * 8 + h) * 2048 * 64;
    const unsigned short* kh  = kb + (size_t)(n * 8 + h) * 2048 * 64;
    const unsigned short* vTh = vT + (size_t)(n * 8 + h) * 64 * 2048;

    bf16x8 qfrag[2];
    {
        const unsigned short* qp = qh + (size_t)(t0 + wave * 16 + l15) * 64;
        qfrag[0] = ld_frag(qp + lg * 8);
        qfrag[1] = ld_frag(qp + 32 + lg * 8);
    }

    const int skey = tid >> 2;            // row 0..63 (K: key | V: dim)
    const int c0   = (tid & 3) * 2;       // first of two 16B chunks
    const int sw0  = (c0 ^ (skey & 7)) * 8;        // swizzled slot, chunk c0
    const int sw1  = ((c0 + 1) ^ (skey & 7)) * 8;  // swizzled slot, chunk c0+1
    const int kx   = l15 & 7;             // read-side chunk XOR

    const int qq = wave * 16 + l15;       // this thread's query (within 64-tile)
    float m_v = -1e30f, l_v = 0.f;
    f32x4 acc_o[4] = {};

    for (int dt = -2; dt <= 2; ++dt) {
        const int kt = qt + dt;
        if (kt < 0 || kt > 31) continue;
        const int s0 = kt * 64;

        {   // stage K + V (reg-based, coalesced), swizzled chunk slots
            const unsigned short* kp = kh + (size_t)(s0 + skey) * 64 + c0 * 8;
            *(uint4*)&Kt[skey * 64 + sw0] = *(const uint4*)kp;
            *(uint4*)&Kt[skey * 64 + sw1] = *(const uint4*)(kp + 8);

            const unsigned short* vp = vTh + (size_t)skey * 2048 + s0 + c0 * 8;
            *(uint4*)&Vt[skey * 64 + sw0] = *(const uint4*)vp;
            *(uint4*)&Vt[skey * 64 + sw1] = *(const uint4*)(vp + 8);
        }
        __syncthreads();

        // ---- S^T = K Q^T (skip fully-masked edge sub-tiles) ----
        f32x4 acc_s[4] = {};
        #pragma unroll
        for (int kstep = 0; kstep < 2; ++kstep) {
            #pragma unroll
            for (int nt = 0; nt < 4; ++nt) {
                if ((dt == -2 && nt < wave) || (dt == 2 && nt > wave)) continue;
                bf16x8 kf = ld_frag(&Kt[(nt * 16 + l15) * 64 +
                                        ((kstep * 4 + lg) ^ kx) * 8]);
                acc_s[nt] = __builtin_amdgcn_mfma_f32_16x16x32_bf16(
                    kf, qfrag[kstep], acc_s[nt], 0, 0, 0);
            }
        }

        // ---- per-thread softmax over 16 scores (one query = l15) ----
        float p[4][4];
        float tm = -1e30f;
        #pragma unroll
        for (int nt = 0; nt < 4; ++nt) {
            #pragma unroll
            for (int r = 0; r < 4; ++r) {
                const int diff = dt * 64 + nt * 16 + qrow + r - qq;
                const bool ok = (diff >= -127) && (diff <= 128);
                const float v = ok ? acc_s[nt][r] : -1e30f;   // scale folded in q
                p[nt][r] = v;
                tm = fmaxf(tm, v);
            }
        }
        tm = fmaxf(tm, __shfl_xor(tm, 16, 64));
        tm = fmaxf(tm, __shfl_xor(tm, 32, 64));
        const float m_new = fmaxf(m_v, tm);
        const float alpha = __expf(m_v - m_new);
        float psum = 0.f;
        #pragma unroll
        for (int nt = 0; nt < 4; ++nt) {
            #pragma unroll
            for (int r = 0; r < 4; ++r) {
                const float e = __expf(p[nt][r] - m_new);
                p[nt][r] = e;
                psum += e;
            }
        }
        psum += __shfl_xor(psum, 16, 64);
        psum += __shfl_xor(psum, 32, 64);
        l_v = l_v * alpha + psum;
        m_v = m_new;

        // rescale acc_o: alpha for query lg*4+r lives in lane (lane&48)|(qrow+r)
        #pragma unroll
        for (int r = 0; r < 4; ++r) {
            const float a_r = __shfl(alpha, (lane & 48) + qrow + r, 64);
            #pragma unroll
            for (int nt = 0; nt < 4; ++nt) acc_o[nt][r] *= a_r;
        }

        // P -> Ps[q][k]: k = nt*16 + qrow + {0..3} contiguous -> packed 8B.
        // Wave-private: no barrier before the pfrag read (same-wave DS order).
        #pragma unroll
        for (int nt = 0; nt < 4; ++nt) {
            uint2 o;
            o.x = packbf2(p[nt][0], p[nt][1]);
            o.y = packbf2(p[nt][2], p[nt][3]);
            *(uint2*)&Ps[wave][l15 * 72 + nt * 16 + qrow] = o;
        }

        bf16x8 pfrag[2];
        pfrag[0] = ld_frag(&Ps[wave][l15 * 72 + lg * 8]);
        pfrag[1] = ld_frag(&Ps[wave][l15 * 72 + 32 + lg * 8]);

        #pragma unroll
        for (int kstep = 0; kstep < 2; ++kstep) {
            #pragma unroll
            for (int nt = 0; nt < 4; ++nt) {
                bf16x8 vf = ld_frag(&Vt[(nt * 16 + l15) * 64 +
                                        ((kstep * 4 + lg) ^ kx) * 8]);
                acc_o[nt] = __builtin_amdgcn_mfma_f32_16x16x32_bf16(
                    pfrag[kstep], vf, acc_o[nt], 0, 0, 0);
            }
        }
        __syncthreads();   // all waves done reading Kt/Vt before next stage
    }

    // 1/l for query lg*4+r lives in lane (lane&48)|(qrow+r)
    const float linv = 1.0f / l_v;
    float inv_l[4];
    #pragma unroll
    for (int r = 0; r < 4; ++r)
        inv_l[r] = __shfl(linv, (lane & 48) + qrow + r, 64);

    #pragma unroll
    for (int r = 0; r < 4; ++r) {
        const int tq = t0 + wave * 16 + qrow + r;
        unsigned short* op = attnout + (size_t)(n * 2048 + tq) * 512 + h * 64;
        #pragma unroll
        for (int nt = 0; nt < 4; ++nt)
            op[nt * 16 + l15] = f2bf(acc_o[nt][r] * inv_l[r]);
    }
}

extern "C" void kernel_launch(void* const* d_in, const int* in_sizes, int n_in,
                              void* d_out, int out_size, void* d_ws, size_t ws_size,
                              hipStream_t stream)
{
    (void)in_sizes; (void)n_in; (void)out_size; (void)ws_size;

    const float* x     = (const float*)d_in[0];
    const float* Wqkv  = (const float*)d_in[1];
    const float* out_w = (const float*)d_in[2];
    const float* out_b = (const float*)d_in[3];
    float* out = (float*)d_out;

    unsigned short* qb    = (unsigned short*)d_ws;          // 4*8*2048*64 bf16
    unsigned short* kbuf  = qb + (size_t)4 * 8 * 2048 * 64; // 4*8*2048*64 bf16
    unsigned short* vTb   = kbuf + (size_t)4 * 8 * 2048 * 64; // 4*8*64*2048
    unsigned short* attnb = vTb + (size_t)4 * 8 * 64 * 2048;  // 8192*512 bf16
    unsigned short* xb    = attnb + (size_t)8192 * 512;     // 8192*512  bf16
    unsigned short* wqkvb = xb + (size_t)8192 * 512;        // 1536*512  bf16
    unsigned short* outwb = wqkvb + (size_t)1536 * 512;     // 512*512   bf16

    // 0) all fp32->bf16 conversions in one launch
    cvt_all<<<5120, 256, 0, stream>>>(x, Wqkv, out_w, xb, wqkvb, outwb);

    // 1) qkv = x @ Wqkv^T with fused RoPE + q-scale -> compact qb/kb + vT
    gemm_bt_mfma<<<dim3(64, 24), 256, 0, stream>>>(xb, wqkvb, nullptr, nullptr,
                                                   8192, 1536, 512, 1, 1,
                                                   vTb, qb, kbuf);
    // 2) flash attention -> attnb bf16
    attn_mfma_kernel<<<dim3(32, 8, 4), 256, 0, stream>>>(qb, kbuf, vTb, attnb);
    // 3) out = attn @ out_w^T + out_b (fp32 out)
    gemm_bt_mfma<<<dim3(64, 8), 256, 0, stream>>>(attnb, outwb, out_b, out,
                                                  8192, 512, 512, 0, 0,
                                                  nullptr, nullptr, nullptr);
}